// Round 10
// baseline (1379.489 us; speedup 1.0000x reference)
//
#include <hip/hip_runtime.h>
#include <hip/hip_bf16.h>
#include <stdint.h>

typedef unsigned short u16;
typedef unsigned int   u32;
typedef float f32x4  __attribute__((ext_vector_type(4)));
typedef short bf16x8 __attribute__((ext_vector_type(8)));

#define NSEQ 800
#define TOUT 12
#define NC   9

// ---- LDS layout (bytes) ----
// B-frags: 24 groups x 64 lanes x 16B = 24576 (block-shared)
// H-scratch per wave: 4 regions (hi,Mt0)(hi,Mt1)(lo,Mt0)(lo,Mt1) x 2048
// k-permutation (h-contraction): k(hid) = 32*(ht>>1) + 2*n + (ht&1), hid = ht*16+n
// cell(m,o,ks) @ ks*1024 + (m&3)*256 + (o>>1)*128 + (m>>2)*32 + (o&1)*16
//   reads (m=n,o=q): uniform over 32 banks; writes (m=q*4+i,o=n>>2): 32 banks 2-way = free
// HAZARD RULE (round-9 bug): ALL ahl loads must complete before ANY h writeback
// in the same step — new-h for ht-pair hp lands in ks=hp, which later hp reads.
#define BSZ   24576
#define RSTR  2048
#define HSZ   8192
#define LDS_TOTAL (BSZ + 2*HSZ)  // 40960 -> 4 blocks/CU -> 2 waves/SIMD

__device__ __forceinline__ u16 f2bf(float f){ union{float f;u32 i;}v; v.f=f; u32 x=v.i; return (u16)((x + 0x7fffu + ((x>>16)&1u))>>16); }
__device__ __forceinline__ u32 pkbf(float a, float b){
  union{ __hip_bfloat162 h2; u32 u; } v;
  v.h2 = __float22bfloat162_rn(float2{a,b});
  return v.u;
}
__device__ __forceinline__ float sigm(float x){ return __builtin_amdgcn_rcpf(1.f+__expf(-x)); }
__device__ __forceinline__ float tanhx(float x){ float e=__expf(2.f*x); return 1.f - 2.f*__builtin_amdgcn_rcpf(e+1.f); }

union BXU { uint4 u; bf16x8 v; };

__global__ __launch_bounds__(128, 2) void rnn_kernel(
  const float* __restrict__ X,
  const float* __restrict__ cw2, const float* __restrict__ cw3, const float* __restrict__ cw4,
  const float* __restrict__ cbv,
  const float* __restrict__ Ewih, const float* __restrict__ Ewhh,
  const float* __restrict__ Ebih, const float* __restrict__ Ebhh,
  const float* __restrict__ Dwih, const float* __restrict__ Dwhh,
  const float* __restrict__ Dbih, const float* __restrict__ Dbhh,
  const float* __restrict__ Lw,   const float* __restrict__ Lb,
  const float* __restrict__ emb,
  float* __restrict__ out)
{
  __shared__ char LDSC[LDS_TOTAL];
  const int tid = threadIdx.x;
  const int wv  = tid >> 6;
  const int l   = tid & 63;
  const int q   = l >> 4;
  const int n   = l & 15;
  const int r   = blockIdx.y;
  const int seqbase = blockIdx.x*64 + wv*32;
  const int HB = BSZ + wv*HSZ;

  const int Kc[NC]={2,2,2,3,3,3,4,4,4};
  const int Dc[NC]={1,2,4,1,2,4,1,2,4};
  const int K = Kc[r], D = Dc[r];
  const int L = 15 - (K-1)*D;

  // ---------- zero per-wave h-scratch ----------
  #pragma unroll
  for (int z=0; z<8; z++) *(uint4*)(LDSC + HB + (z*64+l)*16) = uint4{0,0,0,0};

  // ---------- cooperative B staging (k-permuted whh -> bf16 B-frags) ----------
  // B[k][col] = whh[col][hid(k)], hid(k) = (2*(k>>5)+(k&1))*16 + ((k&31)>>1)
  auto stage_B = [&](const float* __restrict__ whh){
    #pragma unroll 1
    for (int it=0; it<12; it++){
      int slot = it*128 + tid;
      int g = slot >> 6, fl = slot & 63;
      int ks = g/12, nt = g%12;
      int row = nt*16 + (fl&15);
      u32 w[4] = {0,0,0,0};
      #pragma unroll
      for (int j=0;j<8;j++){
        int rem = (fl>>4)*8 + j;                  // k & 31
        int hid = (2*ks + (rem&1))*16 + (rem>>1);
        w[j>>1] |= (u32)f2bf(whh[row*64 + hid]) << ((j&1)*16);
      }
      *(uint4*)(LDSC + (g*64+fl)*16) = uint4{w[0],w[1],w[2],w[3]};
    }
  };

  stage_B(Ewhh + r*192*64);

  // ---------- per-lane x B-frags: conv folded into wih ----------
  BXU bx[12];
  {
    const float* wih = Ewih + r*192*8;
    const float* cw  = (r<3) ? (cw2 + r*128) : (r<6) ? (cw3 + (r-3)*192) : (cw4 + (r-6)*256);
    #pragma unroll 1
    for (int nt=0; nt<12; nt++){
      int row = nt*16 + n;
      float wv8[8];
      #pragma unroll
      for (int o=0;o<8;o++) wv8[o] = wih[row*8+o];
      u32 w[4] = {0,0,0,0};
      if (q < K){
        #pragma unroll
        for (int j=0;j<8;j++){
          float a = 0.f;
          #pragma unroll
          for (int o=0;o<8;o++) a += wv8[o]*cw[(o*8+j)*K + q];
          w[j>>1] |= (u32)f2bf(a) << ((j&1)*16);
        }
      }
      bx[nt].u = uint4{w[0],w[1],w[2],w[3]};
    }
  }

  // ---------- biases (f32), conv bias folded through wih ----------
  float bR4[4], bZ4[4], bNi4[4], bNh4[4];
  {
    const float* bi = Ebih + r*192; const float* bh_ = Ebhh + r*192;
    const float* wih = Ewih + r*192*8; const float* cb = cbv + r*8;
    #pragma unroll
    for (int ht=0; ht<4; ht++){
      int hid = ht*16 + n;
      float cR=0.f,cZ=0.f,cN=0.f;
      #pragma unroll
      for (int o=0;o<8;o++){
        cR += wih[hid*8+o]*cb[o];
        cZ += wih[(64+hid)*8+o]*cb[o];
        cN += wih[(128+hid)*8+o]*cb[o];
      }
      bR4[ht]  = bi[hid]     + bh_[hid]     + cR;
      bZ4[ht]  = bi[64+hid]  + bh_[64+hid]  + cZ;
      bNi4[ht] = bi[128+hid]                + cN;
      bNh4[ht] =               bh_[128+hid];
    }
  }

  float hO[2][4][4];
  #pragma unroll
  for (int Mt=0;Mt<2;Mt++) for (int ht=0;ht<4;ht++) for (int i=0;i<4;i++) hO[Mt][ht][i]=0.f;

  __syncthreads();

  // H-scratch addressing
  const int wbofs = ((n>>3)*128) + (q*32) + (((n>>2)&1)*16) + ((n&3)*4);  // + hp*1024 + i*256
  const int rbofs = (n&3)*256 + (q>>1)*128 + (n>>2)*32 + (q&1)*16;       // + ks*1024

  // ---------- GRU step: ahl hoisted (hazard rule), per-u acc blocking ----------
  auto do_step = [&](bf16x8 ax0, bf16x8 ax1){
    bf16x8 ahl[2][2][2];   // [hilo][ks][Mt] — ALL loaded before any writeback
    #pragma unroll
    for (int ks=0; ks<2; ks++){
      int bo = rbofs + ks*1024;
      #pragma unroll
      for (int Mt=0; Mt<2; Mt++){
        ahl[0][ks][Mt] = *(const bf16x8*)(LDSC + HB +  Mt   *RSTR + bo);
        ahl[1][ks][Mt] = *(const bf16x8*)(LDSC + HB + (2+Mt)*RSTR + bo);
      }
    }
    #pragma unroll
    for (int hp=0; hp<2; hp++){
      float phi0[2][4], plo0[2][4];   // pending u=0 hi/lo (f32)
      #pragma unroll
      for (int u=0; u<2; u++){
        int ht = hp*2+u;
        f32x4 acc[2][4];   // [Mt][R,Z,Ni,Nh], bias-splat init
        #pragma unroll
        for (int Mt=0; Mt<2; Mt++){
          acc[Mt][0] = f32x4{bR4[ht],bR4[ht],bR4[ht],bR4[ht]};
          acc[Mt][1] = f32x4{bZ4[ht],bZ4[ht],bZ4[ht],bZ4[ht]};
          acc[Mt][2] = f32x4{bNi4[ht],bNi4[ht],bNi4[ht],bNi4[ht]};
          acc[Mt][3] = f32x4{bNh4[ht],bNh4[ht],bNh4[ht],bNh4[ht]};
        }
        #pragma unroll
        for (int ks=0; ks<2; ks++){
          bf16x8 fbR = *(const bf16x8*)(LDSC + ((ks*12 +   ht)*64 + l)*16);
          bf16x8 fbZ = *(const bf16x8*)(LDSC + ((ks*12 + 4+ht)*64 + l)*16);
          bf16x8 fbN = *(const bf16x8*)(LDSC + ((ks*12 + 8+ht)*64 + l)*16);
          #pragma unroll
          for (int Mt=0; Mt<2; Mt++){
            acc[Mt][0] = __builtin_amdgcn_mfma_f32_16x16x32_bf16(ahl[0][ks][Mt], fbR, acc[Mt][0], 0,0,0);
            acc[Mt][0] = __builtin_amdgcn_mfma_f32_16x16x32_bf16(ahl[1][ks][Mt], fbR, acc[Mt][0], 0,0,0);
            acc[Mt][1] = __builtin_amdgcn_mfma_f32_16x16x32_bf16(ahl[0][ks][Mt], fbZ, acc[Mt][1], 0,0,0);
            acc[Mt][1] = __builtin_amdgcn_mfma_f32_16x16x32_bf16(ahl[1][ks][Mt], fbZ, acc[Mt][1], 0,0,0);
            acc[Mt][3] = __builtin_amdgcn_mfma_f32_16x16x32_bf16(ahl[0][ks][Mt], fbN, acc[Mt][3], 0,0,0);
            acc[Mt][3] = __builtin_amdgcn_mfma_f32_16x16x32_bf16(ahl[1][ks][Mt], fbN, acc[Mt][3], 0,0,0);
          }
        }
        // x contribution last
        #pragma unroll
        for (int Mt=0; Mt<2; Mt++){
          bf16x8 a = Mt ? ax1 : ax0;
          acc[Mt][0] = __builtin_amdgcn_mfma_f32_16x16x32_bf16(a, bx[ht].v,   acc[Mt][0], 0,0,0);
          acc[Mt][1] = __builtin_amdgcn_mfma_f32_16x16x32_bf16(a, bx[4+ht].v, acc[Mt][1], 0,0,0);
          acc[Mt][2] = __builtin_amdgcn_mfma_f32_16x16x32_bf16(a, bx[8+ht].v, acc[Mt][2], 0,0,0);
        }
        // pointwise
        #pragma unroll
        for (int Mt=0; Mt<2; Mt++){
          #pragma unroll
          for (int i=0; i<4; i++){
            float rr = sigm(acc[Mt][0][i]);
            float zz = sigm(acc[Mt][1][i]);
            float nn = tanhx(acc[Mt][2][i] + rr*acc[Mt][3][i]);
            float ho = hO[Mt][ht][i];
            float hn = nn + zz*(ho - nn);
            hO[Mt][ht][i] = hn;
            u32 hb = __float_as_uint(hn) & 0xffff0000u;
            float hi = __uint_as_float(hb);
            float re = hn - hi;
            if (u==0){ phi0[Mt][i] = hi; plo0[Mt][i] = re; }
            else {
              u32 whi = pkbf(phi0[Mt][i], hi);
              u32 wlo = pkbf(plo0[Mt][i], re);
              int boff = hp*1024 + i*256 + wbofs;
              *(u32*)(LDSC + HB +  Mt   *RSTR + boff) = whi;
              *(u32*)(LDSC + HB + (2+Mt)*RSTR + boff) = wlo;
            }
          }
        }
      }
    }
  };

  // ---------- encoder: A = raw X window (tap q), W~ does conv+wih ----------
  const float* xb0 = X + (size_t)(seqbase +      n)*120 + ((q<K)? q : 0)*D*8;
  const float* xb1 = X + (size_t)(seqbase + 16 + n)*120 + ((q<K)? q : 0)*D*8;
  #pragma unroll 1
  for (int t=0; t<L; t++){
    float4 v00 = *(const float4*)(xb0 + t*8);
    float4 v01 = *(const float4*)(xb0 + t*8 + 4);
    float4 v10 = *(const float4*)(xb1 + t*8);
    float4 v11 = *(const float4*)(xb1 + t*8 + 4);
    BXU a0u, a1u;
    a0u.u = uint4{ pkbf(v00.x,v00.y), pkbf(v00.z,v00.w), pkbf(v01.x,v01.y), pkbf(v01.z,v01.w) };
    a1u.u = uint4{ pkbf(v10.x,v10.y), pkbf(v10.z,v10.w), pkbf(v11.x,v11.y), pkbf(v11.z,v11.w) };
    do_step(a0u.v, a1u.v);
  }

  // ---------- switch to decoder weights ----------
  __syncthreads();
  stage_B(Dwhh + r*192*64);
  {
    const float* dwih = Dwih + r*192;
    #pragma unroll
    for (int nt=0; nt<12; nt++){
      u32 w0 = (q==0) ? (u32)f2bf(dwih[nt*16+n]) : 0u;
      bx[nt].u = uint4{w0,0,0,0};
    }
    const float* bi = Dbih + r*192; const float* bh_ = Dbhh + r*192;
    #pragma unroll
    for (int ht=0; ht<4; ht++){
      int hid = ht*16 + n;
      bR4[ht]  = bi[hid]     + bh_[hid];
      bZ4[ht]  = bi[64+hid]  + bh_[64+hid];
      bNi4[ht] = bi[128+hid];
      bNh4[ht] =               bh_[128+hid];
    }
  }
  __syncthreads();

  // decoder-only constants (kept out of encoder's register pressure)
  float lwr[4];
  #pragma unroll
  for (int ht=0; ht<4; ht++) lwr[ht] = Lw[r*64 + ht*16 + n];
  const float lb_ = Lb[r];
  float wgt;
  {
    int s_ = seqbase + ((n>>2)&1)*16 + q*4 + (n&3);
    int nb = s_ % NSEQ;
    float e[NC], mx = -1e30f;
    #pragma unroll
    for (int c=0;c<NC;c++){ e[c] = emb[nb*NC+c]; mx = fmaxf(mx, e[c]); }
    float sm = 0.f;
    #pragma unroll
    for (int c=0;c<NC;c++) sm += __expf(e[c]-mx);
    wgt = __expf(e[r]-mx) / sm;
  }
  u32 lvw[2];
  lvw[0] = (u32)f2bf(X[(size_t)(seqbase +      n)*120 + 112]);
  lvw[1] = (u32)f2bf(X[(size_t)(seqbase + 16 + n)*120 + 112]);

  // ---------- decoder ----------
  #pragma unroll 1
  for (int t=0; t<TOUT; t++){
    BXU a0u, a1u;
    a0u.u = (q==0) ? uint4{lvw[0],0,0,0} : uint4{0,0,0,0};
    a1u.u = (q==0) ? uint4{lvw[1],0,0,0} : uint4{0,0,0,0};
    do_step(a0u.v, a1u.v);
    float p[8];
    #pragma unroll
    for (int Mt=0; Mt<2; Mt++)
      #pragma unroll
      for (int i=0; i<4; i++)
        p[Mt*4+i] = hO[Mt][0][i]*lwr[0] + hO[Mt][1][i]*lwr[1]
                  + hO[Mt][2][i]*lwr[2] + hO[Mt][3][i]*lwr[3];
    #pragma unroll
    for (int m=1; m<16; m<<=1){
      #pragma unroll
      for (int k=0;k<8;k++) p[k] += __shfl_xor(p[k], m, 64);
    }
    if (n < 8){
      int s_ = seqbase + (n>>2)*16 + q*4 + (n&3);
      atomicAdd(out + (size_t)s_*TOUT + t, wgt*(p[n]+lb_));
    }
    if (t+1 < TOUT){
      float s00 = (n&2) ? p[2] : p[0];
      float s01 = (n&2) ? p[3] : p[1];
      float se0 = ((n&1) ? s01 : s00) + lb_;
      float s10 = (n&2) ? p[6] : p[4];
      float s11 = (n&2) ? p[7] : p[5];
      float se1 = ((n&1) ? s11 : s10) + lb_;
      int src = (n>>2)*16 + (n&3);
      float lv0 = __shfl(se0, src, 64);
      float lv1 = __shfl(se1, src, 64);
      lvw[0] = (u32)f2bf(lv0);
      lvw[1] = (u32)f2bf(lv1);
    }
  }
}

extern "C" void kernel_launch(void* const* d_in, const int* in_sizes, int n_in,
                              void* d_out, int out_size, void* d_ws, size_t ws_size,
                              hipStream_t stream)
{
  float* out = (float*)d_out;
  hipMemsetAsync(out, 0, (size_t)out_size*sizeof(float), stream);

  dim3 g(NSEQ*64/64, NC);   // 800 x 9 blocks, 64 seqs per block (2 waves x 32)
  rnn_kernel<<<g, 128, 0, stream>>>(
    (const float*)d_in[1],
    (const float*)d_in[2], (const float*)d_in[3], (const float*)d_in[4],
    (const float*)d_in[5],
    (const float*)d_in[6], (const float*)d_in[7], (const float*)d_in[8], (const float*)d_in[9],
    (const float*)d_in[10],(const float*)d_in[11],(const float*)d_in[12],(const float*)d_in[13],
    (const float*)d_in[14],(const float*)d_in[15],
    (const float*)d_in[16],
    out);
}

// Round 11
// 1301.624 us; speedup vs baseline: 1.0598x; 1.0598x over previous
//
#include <hip/hip_runtime.h>
#include <hip/hip_bf16.h>
#include <stdint.h>

typedef unsigned short u16;
typedef unsigned int   u32;
typedef float f32x4  __attribute__((ext_vector_type(4)));
typedef short bf16x8 __attribute__((ext_vector_type(8)));

#define NSEQ 800
#define TOUT 12
#define NC   9

// ---- LDS layout (bytes) ----
// B h-frags: 24 groups x 64 lanes x 16B = 24576 (block-shared whh)
// BX x-frags: 12 groups x 64 lanes x 16B = 12288 (block-shared conv*wih / dwih)
// H-scratch per wave: 4 regions (hi,Mt0)(hi,Mt1)(lo,Mt0)(lo,Mt1) x 2048
// k-permutation (h-contraction): k(hid) = 32*(ht>>1) + 2*n + (ht&1), hid = ht*16+n
// cell(m,o,ks) @ ks*1024 + (m&3)*256 + (o>>1)*128 + (m>>2)*32 + (o&1)*16
// HAZARD RULE (round-9 bug): ALL ahl loads must complete before ANY h writeback.
#define BSZ   24576
#define BXOFF 24576
#define HBASE (24576+12288)        // 36864
#define RSTR  2048
#define HSZ   8192
#define LDS_TOTAL (HBASE + 2*HSZ)  // 53248 -> 3 blocks/CU -> ~6 waves/CU

__device__ __forceinline__ u16 f2bf(float f){ union{float f;u32 i;}v; v.f=f; u32 x=v.i; return (u16)((x + 0x7fffu + ((x>>16)&1u))>>16); }
__device__ __forceinline__ u32 pkbf(float a, float b){
  union{ __hip_bfloat162 h2; u32 u; } v;
  v.h2 = __float22bfloat162_rn(float2{a,b});
  return v.u;
}
__device__ __forceinline__ float sigm(float x){ return __builtin_amdgcn_rcpf(1.f+__expf(-x)); }
__device__ __forceinline__ float tanhx(float x){ float e=__expf(2.f*x); return 1.f - 2.f*__builtin_amdgcn_rcpf(e+1.f); }

union BXU { uint4 u; bf16x8 v; };

__global__ __launch_bounds__(128, 2) void rnn_kernel(
  const float* __restrict__ X,
  const float* __restrict__ cw2, const float* __restrict__ cw3, const float* __restrict__ cw4,
  const float* __restrict__ cbv,
  const float* __restrict__ Ewih, const float* __restrict__ Ewhh,
  const float* __restrict__ Ebih, const float* __restrict__ Ebhh,
  const float* __restrict__ Dwih, const float* __restrict__ Dwhh,
  const float* __restrict__ Dbih, const float* __restrict__ Dbhh,
  const float* __restrict__ Lw,   const float* __restrict__ Lb,
  const float* __restrict__ emb,
  float* __restrict__ out)
{
  __shared__ char LDSC[LDS_TOTAL];
  const int tid = threadIdx.x;
  const int wv  = tid >> 6;
  const int l   = tid & 63;
  const int q   = l >> 4;
  const int n   = l & 15;
  const int r   = blockIdx.y;
  const int seqbase = blockIdx.x*64 + wv*32;
  const int HB = HBASE + wv*HSZ;

  const int Kc[NC]={2,2,2,3,3,3,4,4,4};
  const int Dc[NC]={1,2,4,1,2,4,1,2,4};
  const int K = Kc[r], D = Dc[r];
  const int L = 15 - (K-1)*D;

  // ---------- zero per-wave h-scratch ----------
  #pragma unroll
  for (int z=0; z<8; z++) *(uint4*)(LDSC + HB + (z*64+l)*16) = uint4{0,0,0,0};

  // ---------- cooperative B staging (k-permuted whh -> bf16 B-frags) ----------
  auto stage_B = [&](const float* __restrict__ whh){
    #pragma unroll 1
    for (int it=0; it<12; it++){
      int slot = it*128 + tid;
      int g = slot >> 6, fl = slot & 63;
      int ks = g/12, nt = g%12;
      int row = nt*16 + (fl&15);
      u32 w[4] = {0,0,0,0};
      #pragma unroll
      for (int j=0;j<8;j++){
        int rem = (fl>>4)*8 + j;                  // k & 31
        int hid = (2*ks + (rem&1))*16 + (rem>>1);
        w[j>>1] |= (u32)f2bf(whh[row*64 + hid]) << ((j&1)*16);
      }
      *(uint4*)(LDSC + (g*64+fl)*16) = uint4{w[0],w[1],w[2],w[3]};
    }
  };

  // ---------- cooperative BX staging: encoder conv-folded wih ----------
  auto stage_BX_enc = [&](){
    const float* wih = Ewih + r*192*8;
    const float* cw  = (r<3) ? (cw2 + r*128) : (r<6) ? (cw3 + (r-3)*192) : (cw4 + (r-6)*256);
    #pragma unroll 1
    for (int it=0; it<6; it++){
      int slot = it*128 + tid;
      int g = slot >> 6, fl = slot & 63;        // g = nt (0..11)
      int row = g*16 + (fl&15);
      int tap = fl>>4;
      u32 w[4] = {0,0,0,0};
      if (tap < K){
        float wv8[8];
        #pragma unroll
        for (int o=0;o<8;o++) wv8[o] = wih[row*8+o];
        #pragma unroll
        for (int j=0;j<8;j++){
          float a = 0.f;
          #pragma unroll
          for (int o=0;o<8;o++) a += wv8[o]*cw[(o*8+j)*K + tap];
          w[j>>1] |= (u32)f2bf(a) << ((j&1)*16);
        }
      }
      *(uint4*)(LDSC + BXOFF + slot*16) = uint4{w[0],w[1],w[2],w[3]};
    }
  };
  auto stage_BX_dec = [&](){
    const float* dwih = Dwih + r*192;
    #pragma unroll 1
    for (int it=0; it<6; it++){
      int slot = it*128 + tid;
      int g = slot >> 6, fl = slot & 63;
      int row = g*16 + (fl&15);
      u32 w0 = ((fl>>4)==0) ? (u32)f2bf(dwih[row]) : 0u;
      *(uint4*)(LDSC + BXOFF + slot*16) = uint4{w0,0,0,0};
    }
  };

  stage_B(Ewhh + r*192*64);
  stage_BX_enc();

  // ---------- biases (f32), conv bias folded through wih ----------
  float bR4[4], bZ4[4], bNi4[4], bNh4[4];
  {
    const float* bi = Ebih + r*192; const float* bh_ = Ebhh + r*192;
    const float* wih = Ewih + r*192*8; const float* cb = cbv + r*8;
    #pragma unroll
    for (int ht=0; ht<4; ht++){
      int hid = ht*16 + n;
      float cR=0.f,cZ=0.f,cN=0.f;
      #pragma unroll
      for (int o=0;o<8;o++){
        cR += wih[hid*8+o]*cb[o];
        cZ += wih[(64+hid)*8+o]*cb[o];
        cN += wih[(128+hid)*8+o]*cb[o];
      }
      bR4[ht]  = bi[hid]     + bh_[hid]     + cR;
      bZ4[ht]  = bi[64+hid]  + bh_[64+hid]  + cZ;
      bNi4[ht] = bi[128+hid]                + cN;
      bNh4[ht] =               bh_[128+hid];
    }
  }

  float hO[2][4][4];
  #pragma unroll
  for (int Mt=0;Mt<2;Mt++) for (int ht=0;ht<4;ht++) for (int i=0;i<4;i++) hO[Mt][ht][i]=0.f;

  __syncthreads();

  // H-scratch addressing
  const int wbofs = ((n>>3)*128) + (q*32) + (((n>>2)&1)*16) + ((n&3)*4);  // + hp*1024 + i*256
  const int rbofs = (n&3)*256 + (q>>1)*128 + (n>>2)*32 + (q&1)*16;       // + ks*1024

  // ---------- GRU step: ahl hoisted (hazard rule), per-u acc blocking, bx from LDS ----------
  auto do_step = [&](bf16x8 ax0, bf16x8 ax1){
    bf16x8 ahl[2][2][2];   // [hilo][ks][Mt] — ALL loaded before any writeback
    #pragma unroll
    for (int ks=0; ks<2; ks++){
      int bo = rbofs + ks*1024;
      #pragma unroll
      for (int Mt=0; Mt<2; Mt++){
        ahl[0][ks][Mt] = *(const bf16x8*)(LDSC + HB +  Mt   *RSTR + bo);
        ahl[1][ks][Mt] = *(const bf16x8*)(LDSC + HB + (2+Mt)*RSTR + bo);
      }
    }
    #pragma unroll
    for (int hp=0; hp<2; hp++){
      float phi0[2][4], plo0[2][4];   // pending u=0 hi/lo (f32)
      #pragma unroll
      for (int u=0; u<2; u++){
        int ht = hp*2+u;
        f32x4 acc[2][4];   // [Mt][R,Z,Ni,Nh], bias-splat init
        #pragma unroll
        for (int Mt=0; Mt<2; Mt++){
          acc[Mt][0] = f32x4{bR4[ht],bR4[ht],bR4[ht],bR4[ht]};
          acc[Mt][1] = f32x4{bZ4[ht],bZ4[ht],bZ4[ht],bZ4[ht]};
          acc[Mt][2] = f32x4{bNi4[ht],bNi4[ht],bNi4[ht],bNi4[ht]};
          acc[Mt][3] = f32x4{bNh4[ht],bNh4[ht],bNh4[ht],bNh4[ht]};
        }
        #pragma unroll
        for (int ks=0; ks<2; ks++){
          bf16x8 fbR = *(const bf16x8*)(LDSC + ((ks*12 +   ht)*64 + l)*16);
          bf16x8 fbZ = *(const bf16x8*)(LDSC + ((ks*12 + 4+ht)*64 + l)*16);
          bf16x8 fbN = *(const bf16x8*)(LDSC + ((ks*12 + 8+ht)*64 + l)*16);
          #pragma unroll
          for (int Mt=0; Mt<2; Mt++){
            acc[Mt][0] = __builtin_amdgcn_mfma_f32_16x16x32_bf16(ahl[0][ks][Mt], fbR, acc[Mt][0], 0,0,0);
            acc[Mt][0] = __builtin_amdgcn_mfma_f32_16x16x32_bf16(ahl[1][ks][Mt], fbR, acc[Mt][0], 0,0,0);
            acc[Mt][1] = __builtin_amdgcn_mfma_f32_16x16x32_bf16(ahl[0][ks][Mt], fbZ, acc[Mt][1], 0,0,0);
            acc[Mt][1] = __builtin_amdgcn_mfma_f32_16x16x32_bf16(ahl[1][ks][Mt], fbZ, acc[Mt][1], 0,0,0);
            acc[Mt][3] = __builtin_amdgcn_mfma_f32_16x16x32_bf16(ahl[0][ks][Mt], fbN, acc[Mt][3], 0,0,0);
            acc[Mt][3] = __builtin_amdgcn_mfma_f32_16x16x32_bf16(ahl[1][ks][Mt], fbN, acc[Mt][3], 0,0,0);
          }
        }
        // x contribution last (bx frags from LDS)
        {
          bf16x8 bxR = *(const bf16x8*)(LDSC + BXOFF + ((   ht)*64 + l)*16);
          bf16x8 bxZ = *(const bf16x8*)(LDSC + BXOFF + ((4+ht)*64 + l)*16);
          bf16x8 bxN = *(const bf16x8*)(LDSC + BXOFF + ((8+ht)*64 + l)*16);
          #pragma unroll
          for (int Mt=0; Mt<2; Mt++){
            bf16x8 a = Mt ? ax1 : ax0;
            acc[Mt][0] = __builtin_amdgcn_mfma_f32_16x16x32_bf16(a, bxR, acc[Mt][0], 0,0,0);
            acc[Mt][1] = __builtin_amdgcn_mfma_f32_16x16x32_bf16(a, bxZ, acc[Mt][1], 0,0,0);
            acc[Mt][2] = __builtin_amdgcn_mfma_f32_16x16x32_bf16(a, bxN, acc[Mt][2], 0,0,0);
          }
        }
        // pointwise
        #pragma unroll
        for (int Mt=0; Mt<2; Mt++){
          #pragma unroll
          for (int i=0; i<4; i++){
            float rr = sigm(acc[Mt][0][i]);
            float zz = sigm(acc[Mt][1][i]);
            float nn = tanhx(acc[Mt][2][i] + rr*acc[Mt][3][i]);
            float ho = hO[Mt][ht][i];
            float hn = nn + zz*(ho - nn);
            hO[Mt][ht][i] = hn;
            u32 hb = __float_as_uint(hn) & 0xffff0000u;
            float hi = __uint_as_float(hb);
            float re = hn - hi;
            if (u==0){ phi0[Mt][i] = hi; plo0[Mt][i] = re; }
            else {
              u32 whi = pkbf(phi0[Mt][i], hi);
              u32 wlo = pkbf(plo0[Mt][i], re);
              int boff = hp*1024 + i*256 + wbofs;
              *(u32*)(LDSC + HB +  Mt   *RSTR + boff) = whi;
              *(u32*)(LDSC + HB + (2+Mt)*RSTR + boff) = wlo;
            }
          }
        }
      }
    }
  };

  // ---------- encoder: A = raw X window (tap q), W~ does conv+wih ----------
  const float* xb0 = X + (size_t)(seqbase +      n)*120 + ((q<K)? q : 0)*D*8;
  const float* xb1 = X + (size_t)(seqbase + 16 + n)*120 + ((q<K)? q : 0)*D*8;
  #pragma unroll 1
  for (int t=0; t<L; t++){
    float4 v00 = *(const float4*)(xb0 + t*8);
    float4 v01 = *(const float4*)(xb0 + t*8 + 4);
    float4 v10 = *(const float4*)(xb1 + t*8);
    float4 v11 = *(const float4*)(xb1 + t*8 + 4);
    BXU a0u, a1u;
    a0u.u = uint4{ pkbf(v00.x,v00.y), pkbf(v00.z,v00.w), pkbf(v01.x,v01.y), pkbf(v01.z,v01.w) };
    a1u.u = uint4{ pkbf(v10.x,v10.y), pkbf(v10.z,v10.w), pkbf(v11.x,v11.y), pkbf(v11.z,v11.w) };
    do_step(a0u.v, a1u.v);
  }

  // ---------- switch to decoder weights ----------
  __syncthreads();
  stage_B(Dwhh + r*192*64);
  stage_BX_dec();
  {
    const float* bi = Dbih + r*192; const float* bh_ = Dbhh + r*192;
    #pragma unroll
    for (int ht=0; ht<4; ht++){
      int hid = ht*16 + n;
      bR4[ht]  = bi[hid]     + bh_[hid];
      bZ4[ht]  = bi[64+hid]  + bh_[64+hid];
      bNi4[ht] = bi[128+hid];
      bNh4[ht] =               bh_[128+hid];
    }
  }
  __syncthreads();

  // decoder-only constants
  float lwr[4];
  #pragma unroll
  for (int ht=0; ht<4; ht++) lwr[ht] = Lw[r*64 + ht*16 + n];
  const float lb_ = Lb[r];
  float wgt;
  {
    int s_ = seqbase + ((n>>2)&1)*16 + q*4 + (n&3);
    int nb = s_ % NSEQ;
    float e[NC], mx = -1e30f;
    #pragma unroll
    for (int c=0;c<NC;c++){ e[c] = emb[nb*NC+c]; mx = fmaxf(mx, e[c]); }
    float sm = 0.f;
    #pragma unroll
    for (int c=0;c<NC;c++) sm += __expf(e[c]-mx);
    wgt = __expf(e[r]-mx) / sm;
  }
  u32 lvw[2];
  lvw[0] = (u32)f2bf(X[(size_t)(seqbase +      n)*120 + 112]);
  lvw[1] = (u32)f2bf(X[(size_t)(seqbase + 16 + n)*120 + 112]);

  // ---------- decoder ----------
  #pragma unroll 1
  for (int t=0; t<TOUT; t++){
    BXU a0u, a1u;
    a0u.u = (q==0) ? uint4{lvw[0],0,0,0} : uint4{0,0,0,0};
    a1u.u = (q==0) ? uint4{lvw[1],0,0,0} : uint4{0,0,0,0};
    do_step(a0u.v, a1u.v);
    float p[8];
    #pragma unroll
    for (int Mt=0; Mt<2; Mt++)
      #pragma unroll
      for (int i=0; i<4; i++)
        p[Mt*4+i] = hO[Mt][0][i]*lwr[0] + hO[Mt][1][i]*lwr[1]
                  + hO[Mt][2][i]*lwr[2] + hO[Mt][3][i]*lwr[3];
    #pragma unroll
    for (int m=1; m<16; m<<=1){
      #pragma unroll
      for (int k=0;k<8;k++) p[k] += __shfl_xor(p[k], m, 64);
    }
    if (n < 8){
      int s_ = seqbase + (n>>2)*16 + q*4 + (n&3);
      atomicAdd(out + (size_t)s_*TOUT + t, wgt*(p[n]+lb_));
    }
    if (t+1 < TOUT){
      float s00 = (n&2) ? p[2] : p[0];
      float s01 = (n&2) ? p[3] : p[1];
      float se0 = ((n&1) ? s01 : s00) + lb_;
      float s10 = (n&2) ? p[6] : p[4];
      float s11 = (n&2) ? p[7] : p[5];
      float se1 = ((n&1) ? s11 : s10) + lb_;
      int src = (n>>2)*16 + (n&3);
      float lv0 = __shfl(se0, src, 64);
      float lv1 = __shfl(se1, src, 64);
      lvw[0] = (u32)f2bf(lv0);
      lvw[1] = (u32)f2bf(lv1);
    }
  }
}

extern "C" void kernel_launch(void* const* d_in, const int* in_sizes, int n_in,
                              void* d_out, int out_size, void* d_ws, size_t ws_size,
                              hipStream_t stream)
{
  float* out = (float*)d_out;
  hipMemsetAsync(out, 0, (size_t)out_size*sizeof(float), stream);

  dim3 g(NSEQ*64/64, NC);   // 800 x 9 blocks, 64 seqs per block (2 waves x 32)
  rnn_kernel<<<g, 128, 0, stream>>>(
    (const float*)d_in[1],
    (const float*)d_in[2], (const float*)d_in[3], (const float*)d_in[4],
    (const float*)d_in[5],
    (const float*)d_in[6], (const float*)d_in[7], (const float*)d_in[8], (const float*)d_in[9],
    (const float*)d_in[10],(const float*)d_in[11],(const float*)d_in[12],(const float*)d_in[13],
    (const float*)d_in[14],(const float*)d_in[15],
    (const float*)d_in[16],
    out);
}

// Round 12
// 1186.869 us; speedup vs baseline: 1.1623x; 1.0967x over previous
//
#include <hip/hip_runtime.h>
#include <hip/hip_bf16.h>
#include <stdint.h>

typedef unsigned short u16;
typedef unsigned int   u32;
typedef float f32x4  __attribute__((ext_vector_type(4)));
typedef short bf16x8 __attribute__((ext_vector_type(8)));

#define NSEQ 800
#define TOUT 12
#define NC   9

// ---- LDS (per 256-thread block, 16 seqs, 4 waves = 4 gate-quarters) ----
// H: [hilo][seq 16][hid-cell] bf16; cell(seq,kq) @ seq*128 + rot*16, rot=(kq+seq+(seq>>3))&7
// hid<->k map: k=kq*8+j; ht=((kq>>2)<<1)|(j&1); n=((j>>1)&3)|((kq&3)<<2)  (hid=ht*16+n)
// vscr: float[4][16] cross-wave v partials
// HAZARD RULE: all H reads between S1 and S2; all H writes after S2.
#define HILO 2048
#define VSCR 4096
#define LDS_TOTAL 4352

__device__ __forceinline__ u16 f2bf(float f){ union{float f;u32 i;}v; v.f=f; u32 x=v.i; return (u16)((x + 0x7fffu + ((x>>16)&1u))>>16); }
__device__ __forceinline__ u32 pkbf(float a, float b){
  union{ __hip_bfloat162 h2; u32 u; } v;
  v.h2 = __float22bfloat162_rn(float2{a,b});
  return v.u;
}
__device__ __forceinline__ float sigm(float x){ return __builtin_amdgcn_rcpf(1.f+__expf(-x)); }
__device__ __forceinline__ float tanhx(float x){ float e=__expf(2.f*x); return 1.f - 2.f*__builtin_amdgcn_rcpf(e+1.f); }

union BXU { uint4 u; bf16x8 v; };

__global__ __launch_bounds__(256, 3) void rnn_kernel(
  const float* __restrict__ X,
  const float* __restrict__ cw2, const float* __restrict__ cw3, const float* __restrict__ cw4,
  const float* __restrict__ cbv,
  const float* __restrict__ Ewih, const float* __restrict__ Ewhh,
  const float* __restrict__ Ebih, const float* __restrict__ Ebhh,
  const float* __restrict__ Dwih, const float* __restrict__ Dwhh,
  const float* __restrict__ Dbih, const float* __restrict__ Dbhh,
  const float* __restrict__ Lw,   const float* __restrict__ Lb,
  const float* __restrict__ emb,
  float* __restrict__ out)
{
  __shared__ char LDSC[LDS_TOTAL];
  const int tid = threadIdx.x;
  const int ht  = tid >> 6;      // wave id = gate-quarter
  const int l   = tid & 63;
  const int q   = l >> 4;
  const int n   = l & 15;
  const int r   = blockIdx.y;
  const int seqbase = blockIdx.x*16;

  const int Kc[NC]={2,2,2,3,3,3,4,4,4};
  const int Dc[NC]={1,2,4,1,2,4,1,2,4};
  const int K = Kc[r], D = Dc[r];
  const int L = 15 - (K-1)*D;

  // zero H (4096 B = 256 threads x 16 B); vscr overwritten before read
  *(uint4*)(LDSC + tid*16) = uint4{0,0,0,0};

  // ---- whh B-frags in REGISTERS (per-lane k-permuted gather) ----
  bf16x8 bhR[2], bhZ[2], bhN[2];
  auto gather_bh = [&](const float* __restrict__ whh){
    const int rowR = (      ht*16 + n)*64;
    const int rowZ = ( 64 + ht*16 + n)*64;
    const int rowN = (128 + ht*16 + n)*64;
    #pragma unroll
    for (int ks=0; ks<2; ks++){
      u32 wR[4]={0,0,0,0}, wZ[4]={0,0,0,0}, wN[4]={0,0,0,0};
      #pragma unroll
      for (int j=0;j<8;j++){
        int hid = (((ks<<1)|(j&1))<<4) | ((j>>1)&3) | (q<<2);
        u32 sh = (u32)(j&1)*16;
        wR[j>>1] |= (u32)f2bf(whh[rowR + hid]) << sh;
        wZ[j>>1] |= (u32)f2bf(whh[rowZ + hid]) << sh;
        wN[j>>1] |= (u32)f2bf(whh[rowN + hid]) << sh;
      }
      BXU t0,t1,t2;
      t0.u = uint4{wR[0],wR[1],wR[2],wR[3]}; bhR[ks]=t0.v;
      t1.u = uint4{wZ[0],wZ[1],wZ[2],wZ[3]}; bhZ[ks]=t1.v;
      t2.u = uint4{wN[0],wN[1],wN[2],wN[3]}; bhN[ks]=t2.v;
    }
  };
  gather_bh(Ewhh + (size_t)r*192*64);

  // ---- x B-frags (conv folded into wih), registers ----
  BXU bxR, bxZ, bxN;
  {
    const float* wih = Ewih + r*192*8;
    const float* cw  = (r<3) ? (cw2 + r*128) : (r<6) ? (cw3 + (r-3)*192) : (cw4 + (r-6)*256);
    bxR.u = uint4{0,0,0,0}; bxZ.u = uint4{0,0,0,0}; bxN.u = uint4{0,0,0,0};
    if (q < K){
      const int rowR = (      ht*16 + n)*8;
      const int rowZ = ( 64 + ht*16 + n)*8;
      const int rowN = (128 + ht*16 + n)*8;
      float wR8[8], wZ8[8], wN8[8];
      #pragma unroll
      for (int o=0;o<8;o++){ wR8[o]=wih[rowR+o]; wZ8[o]=wih[rowZ+o]; wN8[o]=wih[rowN+o]; }
      u32 aR[4]={0,0,0,0}, aZ[4]={0,0,0,0}, aN[4]={0,0,0,0};
      #pragma unroll
      for (int j=0;j<8;j++){
        float sR=0.f,sZ=0.f,sN=0.f;
        #pragma unroll
        for (int o=0;o<8;o++){
          float c = cw[(o*8+j)*K + q];
          sR += wR8[o]*c; sZ += wZ8[o]*c; sN += wN8[o]*c;
        }
        u32 sh = (u32)(j&1)*16;
        aR[j>>1] |= (u32)f2bf(sR) << sh;
        aZ[j>>1] |= (u32)f2bf(sZ) << sh;
        aN[j>>1] |= (u32)f2bf(sN) << sh;
      }
      bxR.u = uint4{aR[0],aR[1],aR[2],aR[3]};
      bxZ.u = uint4{aZ[0],aZ[1],aZ[2],aZ[3]};
      bxN.u = uint4{aN[0],aN[1],aN[2],aN[3]};
    }
  }

  // ---- biases (f32 scalars per lane: hid = ht*16+n), conv bias folded ----
  float bR, bZ, bNi, bNh_;
  {
    const int hid = ht*16 + n;
    const float* bi = Ebih + r*192; const float* bh2 = Ebhh + r*192;
    const float* wih = Ewih + r*192*8; const float* cb = cbv + r*8;
    float cR=0.f,cZ=0.f,cN=0.f;
    #pragma unroll
    for (int o=0;o<8;o++){
      cR += wih[hid*8+o]*cb[o];
      cZ += wih[(64+hid)*8+o]*cb[o];
      cN += wih[(128+hid)*8+o]*cb[o];
    }
    bR  = bi[hid]     + bh2[hid]     + cR;
    bZ  = bi[64+hid]  + bh2[64+hid]  + cZ;
    bNi = bi[128+hid]                + cN;
    bNh_=               bh2[128+hid];
  }

  float hO[4] = {0.f,0.f,0.f,0.f};

  // A-read cell offsets (m=n): per ks
  const int ra0 = n*128 + ((((  q) + n + (n>>3))&7)<<4);
  const int ra1 = n*128 + ((((4+q) + n + (n>>3))&7)<<4);
  // write: kq/j of this lane's hid
  const int kqw = ((ht>>1)<<2) | (n>>2);
  const int jw2 = ((((n&3)<<1) | (ht&1)) << 1);

  // ---- one GRU step (call after S1; does ahl loads, S2, compute, writes) ----
  auto step_core = [&](bf16x8 ax){
    bf16x8 ahi0 = *(const bf16x8*)(LDSC + ra0);
    bf16x8 ahi1 = *(const bf16x8*)(LDSC + ra1);
    bf16x8 alo0 = *(const bf16x8*)(LDSC + HILO + ra0);
    bf16x8 alo1 = *(const bf16x8*)(LDSC + HILO + ra1);
    __syncthreads();   // S2: all waves' reads done before any write
    f32x4 aR  = f32x4{bR,bR,bR,bR};
    f32x4 aZ  = f32x4{bZ,bZ,bZ,bZ};
    f32x4 aNi = f32x4{bNi,bNi,bNi,bNi};
    f32x4 aNh = f32x4{bNh_,bNh_,bNh_,bNh_};
    aR = __builtin_amdgcn_mfma_f32_16x16x32_bf16(ahi0, bhR[0], aR,0,0,0);
    aR = __builtin_amdgcn_mfma_f32_16x16x32_bf16(alo0, bhR[0], aR,0,0,0);
    aR = __builtin_amdgcn_mfma_f32_16x16x32_bf16(ahi1, bhR[1], aR,0,0,0);
    aR = __builtin_amdgcn_mfma_f32_16x16x32_bf16(alo1, bhR[1], aR,0,0,0);
    aR = __builtin_amdgcn_mfma_f32_16x16x32_bf16(ax,   bxR.v,  aR,0,0,0);
    aZ = __builtin_amdgcn_mfma_f32_16x16x32_bf16(ahi0, bhZ[0], aZ,0,0,0);
    aZ = __builtin_amdgcn_mfma_f32_16x16x32_bf16(alo0, bhZ[0], aZ,0,0,0);
    aZ = __builtin_amdgcn_mfma_f32_16x16x32_bf16(ahi1, bhZ[1], aZ,0,0,0);
    aZ = __builtin_amdgcn_mfma_f32_16x16x32_bf16(alo1, bhZ[1], aZ,0,0,0);
    aZ = __builtin_amdgcn_mfma_f32_16x16x32_bf16(ax,   bxZ.v,  aZ,0,0,0);
    aNh= __builtin_amdgcn_mfma_f32_16x16x32_bf16(ahi0, bhN[0], aNh,0,0,0);
    aNh= __builtin_amdgcn_mfma_f32_16x16x32_bf16(alo0, bhN[0], aNh,0,0,0);
    aNh= __builtin_amdgcn_mfma_f32_16x16x32_bf16(ahi1, bhN[1], aNh,0,0,0);
    aNh= __builtin_amdgcn_mfma_f32_16x16x32_bf16(alo1, bhN[1], aNh,0,0,0);
    aNi= __builtin_amdgcn_mfma_f32_16x16x32_bf16(ax,   bxN.v,  aNi,0,0,0);
    #pragma unroll
    for (int i=0;i<4;i++){
      float rr = sigm(aR[i]);
      float zz = sigm(aZ[i]);
      float nn = tanhx(aNi[i] + rr*aNh[i]);
      float hn = nn + zz*(hO[i]-nn);
      hO[i] = hn;
      u32 hb = __float_as_uint(hn);
      float re = hn - __uint_as_float(hb & 0xffff0000u);
      int seq = q*4+i;
      int wa = seq*128 + (((kqw + seq + (seq>>3))&7)<<4) + jw2;
      *(u16*)(LDSC + wa) = (u16)(hb>>16);
      *(u16*)(LDSC + HILO + wa) = f2bf(re);
    }
  };

  // ---------- encoder ----------
  const float* xb = X + (size_t)(seqbase + n)*120 + ((q<K)? q:0)*D*8;
  #pragma unroll 1
  for (int t=0; t<L; t++){
    float4 v0 = *(const float4*)(xb + t*8);
    float4 v1 = *(const float4*)(xb + t*8 + 4);
    BXU a;
    a.u = uint4{ pkbf(v0.x,v0.y), pkbf(v0.z,v0.w), pkbf(v1.x,v1.y), pkbf(v1.z,v1.w) };
    __syncthreads();   // S1: prior writes visible
    step_core(a.v);
  }

  // ---------- decoder weight switch (registers only, no LDS hazard) ----------
  gather_bh(Dwhh + (size_t)r*192*64);
  {
    const float* dwih = Dwih + r*192;
    const int hid = ht*16 + n;
    bxR.u = uint4{0,0,0,0}; bxZ.u = uint4{0,0,0,0}; bxN.u = uint4{0,0,0,0};
    if (q==0){
      bxR.u.x = (u32)f2bf(dwih[hid]);
      bxZ.u.x = (u32)f2bf(dwih[64+hid]);
      bxN.u.x = (u32)f2bf(dwih[128+hid]);
    }
    const float* bi = Dbih + r*192; const float* bh2 = Dbhh + r*192;
    bR  = bi[hid]     + bh2[hid];
    bZ  = bi[64+hid]  + bh2[64+hid];
    bNi = bi[128+hid];
    bNh_=               bh2[128+hid];
  }
  const float lwr = Lw[r*64 + ht*16 + n];
  const float lb_ = Lb[r];
  float wgt;
  {
    int nb = (seqbase + n) % NSEQ;
    float e[NC], mx = -1e30f;
    #pragma unroll
    for (int c=0;c<NC;c++){ e[c] = emb[nb*NC+c]; mx = fmaxf(mx, e[c]); }
    float sm = 0.f;
    #pragma unroll
    for (int c=0;c<NC;c++) sm += __expf(e[c]-mx);
    wgt = __expf(e[r]-mx) / sm;
  }
  float lv = X[(size_t)(seqbase + n)*120 + 112];   // last0 for seq=n

  // ---------- decoder ----------
  #pragma unroll 1
  for (int t=0; t<TOUT; t++){
    __syncthreads();   // S1
    if (t>0){
      const float* vs = (const float*)(LDSC + VSCR);
      float v = vs[n] + vs[16+n] + vs[32+n] + vs[48+n] + lb_;
      lv = v;
      if (ht==0 && l<16) atomicAdd(out + (size_t)(seqbase+l)*TOUT + (t-1), wgt*v);
    }
    BXU a; a.u = uint4{0,0,0,0};
    if (q==0) a.u.x = (u32)f2bf(lv);
    step_core(a.v);
    // v partials: lane's hid contributes lwr*h to its 4 seqs; reduce over 16-lane group
    float p0 = lwr*hO[0], p1 = lwr*hO[1], p2 = lwr*hO[2], p3 = lwr*hO[3];
    #pragma unroll
    for (int m=1; m<16; m<<=1){
      p0 += __shfl_xor(p0,m,64); p1 += __shfl_xor(p1,m,64);
      p2 += __shfl_xor(p2,m,64); p3 += __shfl_xor(p3,m,64);
    }
    if (n==0){
      float* vs = (float*)(LDSC + VSCR);
      vs[ht*16 + q*4 + 0] = p0; vs[ht*16 + q*4 + 1] = p1;
      vs[ht*16 + q*4 + 2] = p2; vs[ht*16 + q*4 + 3] = p3;
    }
  }
  __syncthreads();
  {
    const float* vs = (const float*)(LDSC + VSCR);
    float v = vs[n] + vs[16+n] + vs[32+n] + vs[48+n] + lb_;
    if (ht==0 && l<16) atomicAdd(out + (size_t)(seqbase+l)*TOUT + (TOUT-1), wgt*v);
  }
}

extern "C" void kernel_launch(void* const* d_in, const int* in_sizes, int n_in,
                              void* d_out, int out_size, void* d_ws, size_t ws_size,
                              hipStream_t stream)
{
  float* out = (float*)d_out;
  hipMemsetAsync(out, 0, (size_t)out_size*sizeof(float), stream);

  dim3 g(51200/16, NC);   // 3200 x 9 blocks; 16 seqs per block, 4 waves (gate-quarters)
  rnn_kernel<<<g, 256, 0, stream>>>(
    (const float*)d_in[1],
    (const float*)d_in[2], (const float*)d_in[3], (const float*)d_in[4],
    (const float*)d_in[5],
    (const float*)d_in[6], (const float*)d_in[7], (const float*)d_in[8], (const float*)d_in[9],
    (const float*)d_in[10],(const float*)d_in[11],(const float*)d_in[12],(const float*)d_in[13],
    (const float*)d_in[14],(const float*)d_in[15],
    (const float*)d_in[16],
    out);
}

// Round 13
// 1185.613 us; speedup vs baseline: 1.1635x; 1.0011x over previous
//
#include <hip/hip_runtime.h>
#include <stdint.h>

typedef unsigned short u16;
typedef unsigned int   u32;
typedef float f32x4  __attribute__((ext_vector_type(4)));
typedef short bf16x8 __attribute__((ext_vector_type(8)));

#define NSEQ 800
#define TOUT 12
#define NC   9
#define LOG2E  1.44269504088896340736f
#define LOG2E2 2.88539008177792681472f

// ---- LDS (per 256-thread block = 4 waves = 4 gate-quarters, 16 seqs) ----
// H ping-pong: buf0 @0, buf1 @4096. Element dword(seq,hid) = bf16(h)|bf16(res)<<16,
//   addr = seq*256 + 16*((hid>>2 + seq)&15) + (hid&3)*4    (k = 2*hid + hilo interleave)
//   -> writes 2-way banked (free), b128 reads phase-minimal (proof in round-13 notes)
// VSCR @8192: float[4][16] cross-wave v partials.
// Single barrier per step: read buf[cur], write buf[alt], swap, __syncthreads().
#define HBUF 4096
#define VSCR 8192
#define LDS_TOTAL 8448

__device__ __forceinline__ u16 f2bf(float f){ union{float f;u32 i;}v; v.f=f; u32 x=v.i; return (u16)((x + 0x7fffu + ((x>>16)&1u))>>16); }

union BXU { uint4 u; bf16x8 v; };

__global__ __launch_bounds__(256, 4) void rnn_kernel(
  const float* __restrict__ X,
  const float* __restrict__ cw2, const float* __restrict__ cw3, const float* __restrict__ cw4,
  const float* __restrict__ cbv,
  const float* __restrict__ Ewih, const float* __restrict__ Ewhh,
  const float* __restrict__ Ebih, const float* __restrict__ Ebhh,
  const float* __restrict__ Dwih, const float* __restrict__ Dwhh,
  const float* __restrict__ Dbih, const float* __restrict__ Dbhh,
  const float* __restrict__ Lw,   const float* __restrict__ Lb,
  const float* __restrict__ emb,
  float* __restrict__ out)
{
  __shared__ char LDSC[LDS_TOTAL];
  const int tid = threadIdx.x;
  const int ht  = tid >> 6;      // wave id = gate-quarter
  const int l   = tid & 63;
  const int q   = l >> 4;
  const int n   = l & 15;
  const int r   = blockIdx.y;
  const int seqbase = blockIdx.x*16;
  const int hid = ht*16 + n;

  const int Kc[NC]={2,2,2,3,3,3,4,4,4};
  const int Dc[NC]={1,2,4,1,2,4,1,2,4};
  const int K = Kc[r], D = Dc[r];
  const int L = 15 - (K-1)*D;

  // zero H buf0 (4096 B = 256 threads x 16 B)
  *(uint4*)(LDSC + tid*16) = uint4{0,0,0,0};

  // ---- whh B-frags in registers: 4 frags/gate, hi/lo-dup dwords, exp2-scaled ----
  bf16x8 bhR[4], bhZ[4], bhN[4];
  auto gather_bh = [&](const float* __restrict__ whh){
    const float* pR = whh + (      hid)*64;
    const float* pZ = whh + ( 64 + hid)*64;
    const float* pN = whh + (128 + hid)*64;
    #pragma unroll
    for (int f=0; f<4; f++){
      u32 wR[4], wZ[4], wN[4];
      #pragma unroll
      for (int e=0;e<4;e++){
        int hh = f*16 + q*4 + e;
        u32 a = (u32)f2bf(LOG2E  * pR[hh]); wR[e] = a | (a<<16);
        u32 b = (u32)f2bf(LOG2E  * pZ[hh]); wZ[e] = b | (b<<16);
        u32 c = (u32)f2bf(LOG2E2 * pN[hh]); wN[e] = c | (c<<16);
      }
      BXU t;
      t.u = uint4{wR[0],wR[1],wR[2],wR[3]}; bhR[f]=t.v;
      t.u = uint4{wZ[0],wZ[1],wZ[2],wZ[3]}; bhZ[f]=t.v;
      t.u = uint4{wN[0],wN[1],wN[2],wN[3]}; bhN[f]=t.v;
    }
  };
  gather_bh(Ewhh + (size_t)r*192*64);

  // ---- x B-frags (conv folded into wih), registers, exp2-scaled ----
  BXU bxR, bxZ, bxN;
  {
    const float* wih = Ewih + r*192*8;
    const float* cw  = (r<3) ? (cw2 + r*128) : (r<6) ? (cw3 + (r-3)*192) : (cw4 + (r-6)*256);
    bxR.u = uint4{0,0,0,0}; bxZ.u = uint4{0,0,0,0}; bxN.u = uint4{0,0,0,0};
    if (q < K){
      const float* rowR = wih + (      hid)*8;
      const float* rowZ = wih + ( 64 + hid)*8;
      const float* rowN = wih + (128 + hid)*8;
      u32 aR[4]={0,0,0,0}, aZ[4]={0,0,0,0}, aN[4]={0,0,0,0};
      #pragma unroll
      for (int j=0;j<8;j++){
        float sR=0.f,sZ=0.f,sN=0.f;
        #pragma unroll
        for (int o=0;o<8;o++){
          float c = cw[(o*8+j)*K + q];
          sR += rowR[o]*c; sZ += rowZ[o]*c; sN += rowN[o]*c;
        }
        u32 sh = (u32)(j&1)*16;
        aR[j>>1] |= (u32)f2bf(LOG2E *sR) << sh;
        aZ[j>>1] |= (u32)f2bf(LOG2E *sZ) << sh;
        aN[j>>1] |= (u32)f2bf(LOG2E2*sN) << sh;
      }
      bxR.u = uint4{aR[0],aR[1],aR[2],aR[3]};
      bxZ.u = uint4{aZ[0],aZ[1],aZ[2],aZ[3]};
      bxN.u = uint4{aN[0],aN[1],aN[2],aN[3]};
    }
  }

  // ---- biases (scaled), conv bias folded ----
  float bR, bZ, bNi, bNh_;
  {
    const float* bi = Ebih + r*192; const float* bh2 = Ebhh + r*192;
    const float* wih = Ewih + r*192*8; const float* cb = cbv + r*8;
    float cR=0.f,cZ=0.f,cN=0.f;
    #pragma unroll
    for (int o=0;o<8;o++){
      cR += wih[hid*8+o]*cb[o];
      cZ += wih[(64+hid)*8+o]*cb[o];
      cN += wih[(128+hid)*8+o]*cb[o];
    }
    bR  = LOG2E  * (bi[hid]     + bh2[hid]     + cR);
    bZ  = LOG2E  * (bi[64+hid]  + bh2[64+hid]  + cZ);
    bNi = LOG2E2 * (bi[128+hid]                + cN);
    bNh_= LOG2E2 *                bh2[128+hid];
  }

  float hO[4] = {0.f,0.f,0.f,0.f};

  // step-invariant LDS addresses
  int ra[4], wa[4];
  #pragma unroll
  for (int f=0;f<4;f++) ra[f] = n*256 + (((f*4 + q + n)&15)<<4);
  #pragma unroll
  for (int i=0;i<4;i++){
    int seq = q*4+i;
    wa[i] = seq*256 + ((((hid>>2) + seq)&15)<<4) + ((hid&3)<<2);
  }
  int hr = 0, hw = HBUF;

  // ---- one GRU step; caller must __syncthreads() after ----
  auto step_core = [&](bf16x8 ax){
    const char* rp = LDSC + hr;
    bf16x8 a0 = *(const bf16x8*)(rp + ra[0]);
    bf16x8 a1 = *(const bf16x8*)(rp + ra[1]);
    bf16x8 a2 = *(const bf16x8*)(rp + ra[2]);
    bf16x8 a3 = *(const bf16x8*)(rp + ra[3]);
    f32x4 aR  = f32x4{bR,bR,bR,bR};
    f32x4 aZ  = f32x4{bZ,bZ,bZ,bZ};
    f32x4 aNi = f32x4{bNi,bNi,bNi,bNi};
    f32x4 aNh = f32x4{bNh_,bNh_,bNh_,bNh_};
    aR = __builtin_amdgcn_mfma_f32_16x16x32_bf16(a0, bhR[0], aR,0,0,0);
    aR = __builtin_amdgcn_mfma_f32_16x16x32_bf16(a1, bhR[1], aR,0,0,0);
    aR = __builtin_amdgcn_mfma_f32_16x16x32_bf16(a2, bhR[2], aR,0,0,0);
    aR = __builtin_amdgcn_mfma_f32_16x16x32_bf16(a3, bhR[3], aR,0,0,0);
    aR = __builtin_amdgcn_mfma_f32_16x16x32_bf16(ax, bxR.v,  aR,0,0,0);
    aZ = __builtin_amdgcn_mfma_f32_16x16x32_bf16(a0, bhZ[0], aZ,0,0,0);
    aZ = __builtin_amdgcn_mfma_f32_16x16x32_bf16(a1, bhZ[1], aZ,0,0,0);
    aZ = __builtin_amdgcn_mfma_f32_16x16x32_bf16(a2, bhZ[2], aZ,0,0,0);
    aZ = __builtin_amdgcn_mfma_f32_16x16x32_bf16(a3, bhZ[3], aZ,0,0,0);
    aZ = __builtin_amdgcn_mfma_f32_16x16x32_bf16(ax, bxZ.v,  aZ,0,0,0);
    aNh= __builtin_amdgcn_mfma_f32_16x16x32_bf16(a0, bhN[0], aNh,0,0,0);
    aNh= __builtin_amdgcn_mfma_f32_16x16x32_bf16(a1, bhN[1], aNh,0,0,0);
    aNh= __builtin_amdgcn_mfma_f32_16x16x32_bf16(a2, bhN[2], aNh,0,0,0);
    aNh= __builtin_amdgcn_mfma_f32_16x16x32_bf16(a3, bhN[3], aNh,0,0,0);
    aNi= __builtin_amdgcn_mfma_f32_16x16x32_bf16(ax, bxN.v,  aNi,0,0,0);
    char* wp = LDSC + hw;
    #pragma unroll
    for (int i=0;i<4;i++){
      float rr = __builtin_amdgcn_rcpf(1.f + __builtin_amdgcn_exp2f(-aR[i]));
      float zz = __builtin_amdgcn_rcpf(1.f + __builtin_amdgcn_exp2f(-aZ[i]));
      float y  = aNi[i] + rr*aNh[i];
      float nn = 1.f - 2.f*__builtin_amdgcn_rcpf(__builtin_amdgcn_exp2f(y) + 1.f);
      float hn = nn + zz*(hO[i]-nn);
      hO[i] = hn;
      u32 hnb = __float_as_uint(hn);
      float hif = __uint_as_float(hnb & 0xffff0000u);
      u32 reb = __float_as_uint(hn - hif);
      *(u32*)(wp + wa[i]) = __builtin_amdgcn_perm(reb, hnb, 0x07060302u);
    }
    int t_ = hr; hr = hw; hw = t_;
  };

  // ---------- encoder ----------
  const float* xb = X + (size_t)(seqbase + n)*120 + ((q<K)? q:0)*D*8;
  __syncthreads();
  #pragma unroll 1
  for (int t=0; t<L; t++){
    float4 v0 = *(const float4*)(xb + t*8);
    float4 v1 = *(const float4*)(xb + t*8 + 4);
    BXU a;
    a.u.x = __builtin_amdgcn_perm(__float_as_uint(v0.y), __float_as_uint(v0.x), 0x07060302u);
    a.u.y = __builtin_amdgcn_perm(__float_as_uint(v0.w), __float_as_uint(v0.z), 0x07060302u);
    a.u.z = __builtin_amdgcn_perm(__float_as_uint(v1.y), __float_as_uint(v1.x), 0x07060302u);
    a.u.w = __builtin_amdgcn_perm(__float_as_uint(v1.w), __float_as_uint(v1.z), 0x07060302u);
    step_core(a.v);
    __syncthreads();
  }

  // ---------- decoder weight switch (registers only) ----------
  gather_bh(Dwhh + (size_t)r*192*64);
  {
    const float* dwih = Dwih + r*192;
    bxR.u = uint4{0,0,0,0}; bxZ.u = uint4{0,0,0,0}; bxN.u = uint4{0,0,0,0};
    if (q==0){
      bxR.u.x = (u32)f2bf(LOG2E *dwih[hid]);
      bxZ.u.x = (u32)f2bf(LOG2E *dwih[64+hid]);
      bxN.u.x = (u32)f2bf(LOG2E2*dwih[128+hid]);
    }
    const float* bi = Dbih + r*192; const float* bh2 = Dbhh + r*192;
    bR  = LOG2E  * (bi[hid]     + bh2[hid]);
    bZ  = LOG2E  * (bi[64+hid]  + bh2[64+hid]);
    bNi = LOG2E2 *  bi[128+hid];
    bNh_= LOG2E2 *  bh2[128+hid];
  }
  const float lwr = Lw[r*64 + hid];
  const float lb_ = Lb[r];
  float wgt;
  {
    int nb = (seqbase + n) % NSEQ;
    float e[NC], mx = -1e30f;
    #pragma unroll
    for (int c=0;c<NC;c++){ e[c] = emb[nb*NC+c]; mx = fmaxf(mx, e[c]); }
    float sm = 0.f;
    #pragma unroll
    for (int c=0;c<NC;c++) sm += __expf(e[c]-mx);
    wgt = __expf(e[r]-mx) / sm;
  }
  float lv = X[(size_t)(seqbase + n)*120 + 112];   // last0 for seq=n

  // ---------- decoder ----------
  #pragma unroll 1
  for (int t=0; t<TOUT; t++){
    if (t>0){
      const float* vs = (const float*)(LDSC + VSCR);
      float v = vs[n] + vs[16+n] + vs[32+n] + vs[48+n] + lb_;
      lv = v;
      if (ht==0 && l<16) atomicAdd(out + (size_t)(seqbase+l)*TOUT + (t-1), wgt*v);
    }
    BXU a; a.u = uint4{0,0,0,0};
    if (q==0) a.u.x = __float_as_uint(lv) >> 16;   // bf16-trunc(lv) at k=0
    step_core(a.v);
    float p0 = lwr*hO[0], p1 = lwr*hO[1], p2 = lwr*hO[2], p3 = lwr*hO[3];
    #pragma unroll
    for (int m=1; m<16; m<<=1){
      p0 += __shfl_xor(p0,m,64); p1 += __shfl_xor(p1,m,64);
      p2 += __shfl_xor(p2,m,64); p3 += __shfl_xor(p3,m,64);
    }
    if (n==0){
      float* vs = (float*)(LDSC + VSCR);
      vs[ht*16 + q*4 + 0] = p0; vs[ht*16 + q*4 + 1] = p1;
      vs[ht*16 + q*4 + 2] = p2; vs[ht*16 + q*4 + 3] = p3;
    }
    __syncthreads();
  }
  {
    const float* vs = (const float*)(LDSC + VSCR);
    float v = vs[n] + vs[16+n] + vs[32+n] + vs[48+n] + lb_;
    if (ht==0 && l<16) atomicAdd(out + (size_t)(seqbase+l)*TOUT + (TOUT-1), wgt*v);
  }
}

extern "C" void kernel_launch(void* const* d_in, const int* in_sizes, int n_in,
                              void* d_out, int out_size, void* d_ws, size_t ws_size,
                              hipStream_t stream)
{
  float* out = (float*)d_out;
  hipMemsetAsync(out, 0, (size_t)out_size*sizeof(float), stream);

  dim3 g(51200/16, NC);   // 3200 x 9 blocks; 16 seqs per block, 4 waves (gate-quarters)
  rnn_kernel<<<g, 256, 0, stream>>>(
    (const float*)d_in[1],
    (const float*)d_in[2], (const float*)d_in[3], (const float*)d_in[4],
    (const float*)d_in[5],
    (const float*)d_in[6], (const float*)d_in[7], (const float*)d_in[8], (const float*)d_in[9],
    (const float*)d_in[10],(const float*)d_in[11],(const float*)d_in[12],(const float*)d_in[13],
    (const float*)d_in[14],(const float*)d_in[15],
    (const float*)d_in[16],
    out);
}